// Round 3
// baseline (489.537 us; speedup 1.0000x reference)
//
#include <hip/hip_runtime.h>
#include <math.h>

#define LAYERS 20
#define CS_FLOATS 480   // 20 layers * 12 qubits * {cos,sin}

// ---------------------------------------------------------------------------
// Pre-kernel: accurate cos/sin of theta/2 for layers 1..20 (weights[1:21]).
// ---------------------------------------------------------------------------
__global__ void cs_precompute(const float* __restrict__ qp, float* __restrict__ cs) {
    int i = threadIdx.x;
    if (i < 240) {
        float t = 0.5f * qp[12 + i];
        cs[2 * i]     = cosf(t);
        cs[2 * i + 1] = sinf(t);
    }
}

// ---------------------------------------------------------------------------
// X-macro machinery. State = 64 NAMED scalars v0..v63 (never an array:
// an alloca'd float[64] is not SROA-promoted before loop unrolling and the
// backend keeps it in scratch -> 18MB/dispatch scratch writes, 480us. Named
// scalars force register allocation.)
// Layout: amplitude i: reg r = i>>6 (qubits 0..5 = reg bits 5..0),
//         lane = i&63 (qubits 6..11 = lane bits 5..0).
// ---------------------------------------------------------------------------
#define ALL64(F) F(0) F(1) F(2) F(3) F(4) F(5) F(6) F(7) F(8) F(9) F(10) F(11) \
  F(12) F(13) F(14) F(15) F(16) F(17) F(18) F(19) F(20) F(21) F(22) F(23) \
  F(24) F(25) F(26) F(27) F(28) F(29) F(30) F(31) F(32) F(33) F(34) F(35) \
  F(36) F(37) F(38) F(39) F(40) F(41) F(42) F(43) F(44) F(45) F(46) F(47) \
  F(48) F(49) F(50) F(51) F(52) F(53) F(54) F(55) F(56) F(57) F(58) F(59) \
  F(60) F(61) F(62) F(63)
#define LO32(F) F(0) F(1) F(2) F(3) F(4) F(5) F(6) F(7) F(8) F(9) F(10) F(11) \
  F(12) F(13) F(14) F(15) F(16) F(17) F(18) F(19) F(20) F(21) F(22) F(23) \
  F(24) F(25) F(26) F(27) F(28) F(29) F(30) F(31)
#define HI32(F) F(32) F(33) F(34) F(35) F(36) F(37) F(38) F(39) F(40) F(41) \
  F(42) F(43) F(44) F(45) F(46) F(47) F(48) F(49) F(50) F(51) F(52) F(53) \
  F(54) F(55) F(56) F(57) F(58) F(59) F(60) F(61) F(62) F(63)

// rotation pairs (a, a|m) for each reg-qubit mask m (a & m == 0)
#define PAIRS32(F) F(0,32) F(1,33) F(2,34) F(3,35) F(4,36) F(5,37) F(6,38) F(7,39) \
  F(8,40) F(9,41) F(10,42) F(11,43) F(12,44) F(13,45) F(14,46) F(15,47) \
  F(16,48) F(17,49) F(18,50) F(19,51) F(20,52) F(21,53) F(22,54) F(23,55) \
  F(24,56) F(25,57) F(26,58) F(27,59) F(28,60) F(29,61) F(30,62) F(31,63)
#define PAIRS16(F) F(0,16) F(1,17) F(2,18) F(3,19) F(4,20) F(5,21) F(6,22) F(7,23) \
  F(8,24) F(9,25) F(10,26) F(11,27) F(12,28) F(13,29) F(14,30) F(15,31) \
  F(32,48) F(33,49) F(34,50) F(35,51) F(36,52) F(37,53) F(38,54) F(39,55) \
  F(40,56) F(41,57) F(42,58) F(43,59) F(44,60) F(45,61) F(46,62) F(47,63)
#define PAIRS8(F) F(0,8) F(1,9) F(2,10) F(3,11) F(4,12) F(5,13) F(6,14) F(7,15) \
  F(16,24) F(17,25) F(18,26) F(19,27) F(20,28) F(21,29) F(22,30) F(23,31) \
  F(32,40) F(33,41) F(34,42) F(35,43) F(36,44) F(37,45) F(38,46) F(39,47) \
  F(48,56) F(49,57) F(50,58) F(51,59) F(52,60) F(53,61) F(54,62) F(55,63)
#define PAIRS4(F) F(0,4) F(1,5) F(2,6) F(3,7) F(8,12) F(9,13) F(10,14) F(11,15) \
  F(16,20) F(17,21) F(18,22) F(19,23) F(24,28) F(25,29) F(26,30) F(27,31) \
  F(32,36) F(33,37) F(34,38) F(35,39) F(40,44) F(41,45) F(42,46) F(43,47) \
  F(48,52) F(49,53) F(50,54) F(51,55) F(56,60) F(57,61) F(58,62) F(59,63)
#define PAIRS2(F) F(0,2) F(1,3) F(4,6) F(5,7) F(8,10) F(9,11) F(12,14) F(13,15) \
  F(16,18) F(17,19) F(20,22) F(21,23) F(24,26) F(25,27) F(28,30) F(29,31) \
  F(32,34) F(33,35) F(36,38) F(37,39) F(40,42) F(41,43) F(44,46) F(45,47) \
  F(48,50) F(49,51) F(52,54) F(53,55) F(56,58) F(57,59) F(60,62) F(61,63)
#define PAIRS1(F) F(0,1) F(2,3) F(4,5) F(6,7) F(8,9) F(10,11) F(12,13) F(14,15) \
  F(16,17) F(18,19) F(20,21) F(22,23) F(24,25) F(26,27) F(28,29) F(30,31) \
  F(32,33) F(34,35) F(36,37) F(38,39) F(40,41) F(42,43) F(44,45) F(46,47) \
  F(48,49) F(50,51) F(52,53) F(54,55) F(56,57) F(58,59) F(60,61) F(62,63)

// ---------------------------------------------------------------------------
template <bool PRE>
__global__ __launch_bounds__(256, 4)
void qsim(const float* __restrict__ feats,
          const float* __restrict__ qp,
          const float* __restrict__ cs,
          float* __restrict__ out)
{
    const int lane = threadIdx.x & 63;
    const int row  = blockIdx.x * 4 + (threadIdx.x >> 6);

    // entangler lane-permutation bpermute byte addresses (GF(2)-linear map)
    const int sl0 = lane ^ (lane >> 1) ^ ((lane >> 2) & 5);
    const int addr0 = sl0 << 2;
    const int addr1 = (sl0 ^ 48) << 2;

#define DCL(r) float v##r;
    ALL64(DCL)
#undef DCL

    // ---- load + tanh + amplitude embedding ----
    const float* fr = feats + (size_t)row * 2048;
    float nrm = 0.f;
#define LD(r) { float x_ = tanhf(fr[((r) << 6) + lane]) * 1.5707963267948966f; \
                v##r = x_; nrm += x_ * x_; }
    LO32(LD)
#undef LD
#pragma unroll
    for (int m = 32; m >= 1; m >>= 1) nrm += __shfl_xor(nrm, m, 64);
    nrm += 512.0f;                       // 2048 pad elements of 0.5^2
    const float inv  = rsqrtf(nrm);
    const float padv = 0.5f * inv;
#define SC(r) v##r *= inv;
    LO32(SC)
#undef SC
#define PD(r) v##r = padv;
    HI32(PD)
#undef PD

    // ---- 20 circuit layers ----
    for (int l = 0; l < LAYERS; ++l) {
        // ---- entangling layer: in-place reg-cycle rename fused with lane bpermute
#define BPV(a, x) __int_as_float(__builtin_amdgcn_ds_bpermute( \
                      (((a) & 1) ? addr1 : addr0), __float_as_int(x)))
#define FIX(a) v##a = BPV(a, v##a);
#define CYC2(a,b) { float t_ = v##a; v##a = BPV(a, v##b); v##b = BPV(b, t_); }
#define CYC4(a,b,c,d) { float t_ = v##a; v##a = BPV(a, v##b); \
        v##b = BPV(b, v##c); v##c = BPV(c, v##d); v##d = BPV(d, t_); }
#define CYC8(a,b,c,d,e,f,g,h) { float t_ = v##a; v##a = BPV(a, v##b); \
        v##b = BPV(b, v##c); v##c = BPV(c, v##d); v##d = BPV(d, v##e); \
        v##e = BPV(e, v##f); v##f = BPV(f, v##g); v##g = BPV(g, v##h); \
        v##h = BPV(h, t_); }
        FIX(0) FIX(1)
        CYC2(2, 3)
        CYC4(4, 7, 5, 6)
        CYC4(8, 12, 11, 14)
        CYC4(9, 13, 10, 15)
        CYC8(16, 28, 23, 25, 17, 29, 22, 24)
        CYC8(18, 31, 21, 26, 19, 30, 20, 27)
        CYC8(32, 48, 44, 59, 34, 51, 46, 56)
        CYC8(33, 49, 45, 58, 35, 50, 47, 57)
        CYC8(36, 55, 41, 61, 38, 52, 43, 62)
        CYC8(37, 54, 40, 60, 39, 53, 42, 63)
#undef BPV
#undef FIX
#undef CYC2
#undef CYC4
#undef CYC8

        const float* csl = cs + l * 24;

        // ---- RY on reg-bit qubits j = 0..5 (mask 32 >> j) — pure VALU
#define RYP(a,b) { float a0_ = v##a, a1_ = v##b; \
        v##a = c_ * a0_ - s_ * a1_; v##b = s_ * a0_ + c_ * a1_; }
#define RYREG(J, LIST) { float c_, s_; \
        if constexpr (PRE) { c_ = csl[2*(J)]; s_ = csl[2*(J)+1]; } \
        else { float t_ = 0.5f * qp[12 + l*12 + (J)]; __sincosf(t_, &s_, &c_); } \
        LIST(RYP) }
        RYREG(0, PAIRS32)
        RYREG(1, PAIRS16)
        RYREG(2, PAIRS8)
        RYREG(3, PAIRS4)
        RYREG(4, PAIRS2)
        RYREG(5, PAIRS1)
#undef RYREG
#undef RYP

        // ---- RY on lane-bit qubits j = 6..11 (lane mask 32 >> (j-6))
#define LRY(r) { float p_ = __shfl_xor(v##r, m, 64); v##r = c_ * v##r + ssel_ * p_; }
#pragma unroll
        for (int j = 0; j < 6; ++j) {
            float c_, s_;
            if constexpr (PRE) { c_ = csl[12 + 2*j]; s_ = csl[12 + 2*j + 1]; }
            else { float t_ = 0.5f * qp[12 + l*12 + 6 + j]; __sincosf(t_, &s_, &c_); }
            const int m = 32 >> j;
            const float ssel_ = (lane & m) ? s_ : -s_;
            ALL64(LRY)
        }
#undef LRY
    }

    // ---- PauliZ expectation values ----
    float T = 0.f;
#define SQT(r) v##r *= v##r; T += v##r;
    ALL64(SQT)
#undef SQT

    float part[12];
#define ADDB(a,b) + v##b
    { float S;
      S = 0.f PAIRS32(ADDB); part[0] = T - 2.f * S;
      S = 0.f PAIRS16(ADDB); part[1] = T - 2.f * S;
      S = 0.f PAIRS8(ADDB);  part[2] = T - 2.f * S;
      S = 0.f PAIRS4(ADDB);  part[3] = T - 2.f * S;
      S = 0.f PAIRS2(ADDB);  part[4] = T - 2.f * S;
      S = 0.f PAIRS1(ADDB);  part[5] = T - 2.f * S; }
#undef ADDB
#pragma unroll
    for (int q = 6; q < 12; ++q) {
        const int m = 32 >> (q - 6);
        part[q] = (lane & m) ? -T : T;
    }
#pragma unroll
    for (int q = 0; q < 12; ++q) {
#pragma unroll
        for (int m2 = 32; m2 >= 1; m2 >>= 1) part[q] += __shfl_xor(part[q], m2, 64);
    }
    if (lane == 0) {
#pragma unroll
        for (int q = 0; q < 12; ++q) out[row * 12 + q] = part[q];
    }
}

// ---------------------------------------------------------------------------
extern "C" void kernel_launch(void* const* d_in, const int* in_sizes, int n_in,
                              void* d_out, int out_size, void* d_ws, size_t ws_size,
                              hipStream_t stream) {
    (void)in_sizes; (void)n_in; (void)out_size;
    const float* feats = (const float*)d_in[0];   // (4096, 2048) fp32
    const float* qp    = (const float*)d_in[1];   // (252,) fp32
    float* out = (float*)d_out;                   // (4096, 12) fp32

    if (ws_size >= CS_FLOATS * sizeof(float)) {
        float* cs = (float*)d_ws;
        cs_precompute<<<1, 256, 0, stream>>>(qp, cs);
        qsim<true><<<1024, 256, 0, stream>>>(feats, qp, cs, out);
    } else {
        qsim<false><<<1024, 256, 0, stream>>>(feats, qp, nullptr, out);
    }
}

// Round 5
// 481.981 us; speedup vs baseline: 1.0157x; 1.0157x over previous
//
#include <hip/hip_runtime.h>
#include <math.h>

#define LAYERS 20
#define CS_FLOATS 480   // 20 layers * 12 qubits * {cos,sin}

// ---------------------------------------------------------------------------
// Pre-kernel: accurate cos/sin of theta/2 for layers 1..20 (weights[1:21]).
// ---------------------------------------------------------------------------
__global__ void cs_precompute(const float* __restrict__ qp, float* __restrict__ cs) {
    int i = threadIdx.x;
    if (i < 240) {
        float t = 0.5f * qp[12 + i];
        cs[2 * i]     = cosf(t);
        cs[2 * i + 1] = sinf(t);
    }
}

// ---------------------------------------------------------------------------
// X-macro machinery. State = 64 NAMED scalars v0..v63.
// R1-R3 lesson: with only __launch_bounds__(256,4) (a MIN waves/EU), the
// AMDGPU backend targets MAX occupancy (8 waves/EU -> 64 VGPR budget) and
// spills the whole state to scratch (17MB HBM write-back, 470us). The grid
// (4096 waves / 1024 SIMDs) caps real occupancy at 4 waves/SIMD anyway, so
// amdgpu_waves_per_eu(4,4) forces a 128-VGPR budget at zero occupancy cost.
// Layout: amplitude i: reg r = i>>6 (qubits 0..5 = reg bits 5..0),
//         lane = i&63 (qubits 6..11 = lane bits 5..0).
// ---------------------------------------------------------------------------
#define ALL64(F) F(0) F(1) F(2) F(3) F(4) F(5) F(6) F(7) F(8) F(9) F(10) F(11) \
  F(12) F(13) F(14) F(15) F(16) F(17) F(18) F(19) F(20) F(21) F(22) F(23) \
  F(24) F(25) F(26) F(27) F(28) F(29) F(30) F(31) F(32) F(33) F(34) F(35) \
  F(36) F(37) F(38) F(39) F(40) F(41) F(42) F(43) F(44) F(45) F(46) F(47) \
  F(48) F(49) F(50) F(51) F(52) F(53) F(54) F(55) F(56) F(57) F(58) F(59) \
  F(60) F(61) F(62) F(63)
#define LO32(F) F(0) F(1) F(2) F(3) F(4) F(5) F(6) F(7) F(8) F(9) F(10) F(11) \
  F(12) F(13) F(14) F(15) F(16) F(17) F(18) F(19) F(20) F(21) F(22) F(23) \
  F(24) F(25) F(26) F(27) F(28) F(29) F(30) F(31)
#define HI32(F) F(32) F(33) F(34) F(35) F(36) F(37) F(38) F(39) F(40) F(41) \
  F(42) F(43) F(44) F(45) F(46) F(47) F(48) F(49) F(50) F(51) F(52) F(53) \
  F(54) F(55) F(56) F(57) F(58) F(59) F(60) F(61) F(62) F(63)

// rotation pairs (a, a|m) for each reg-qubit mask m (a & m == 0)
#define PAIRS32(F) F(0,32) F(1,33) F(2,34) F(3,35) F(4,36) F(5,37) F(6,38) F(7,39) \
  F(8,40) F(9,41) F(10,42) F(11,43) F(12,44) F(13,45) F(14,46) F(15,47) \
  F(16,48) F(17,49) F(18,50) F(19,51) F(20,52) F(21,53) F(22,54) F(23,55) \
  F(24,56) F(25,57) F(26,58) F(27,59) F(28,60) F(29,61) F(30,62) F(31,63)
#define PAIRS16(F) F(0,16) F(1,17) F(2,18) F(3,19) F(4,20) F(5,21) F(6,22) F(7,23) \
  F(8,24) F(9,25) F(10,26) F(11,27) F(12,28) F(13,29) F(14,30) F(15,31) \
  F(32,48) F(33,49) F(34,50) F(35,51) F(36,52) F(37,53) F(38,54) F(39,55) \
  F(40,56) F(41,57) F(42,58) F(43,59) F(44,60) F(45,61) F(46,62) F(47,63)
#define PAIRS8(F) F(0,8) F(1,9) F(2,10) F(3,11) F(4,12) F(5,13) F(6,14) F(7,15) \
  F(16,24) F(17,25) F(18,26) F(19,27) F(20,28) F(21,29) F(22,30) F(23,31) \
  F(32,40) F(33,41) F(34,42) F(35,43) F(36,44) F(37,45) F(38,46) F(39,47) \
  F(48,56) F(49,57) F(50,58) F(51,59) F(52,60) F(53,61) F(54,62) F(55,63)
#define PAIRS4(F) F(0,4) F(1,5) F(2,6) F(3,7) F(8,12) F(9,13) F(10,14) F(11,15) \
  F(16,20) F(17,21) F(18,22) F(19,23) F(24,28) F(25,29) F(26,30) F(27,31) \
  F(32,36) F(33,37) F(34,38) F(35,39) F(40,44) F(41,45) F(42,46) F(43,47) \
  F(48,52) F(49,53) F(50,54) F(51,55) F(56,60) F(57,61) F(58,62) F(59,63)
#define PAIRS2(F) F(0,2) F(1,3) F(4,6) F(5,7) F(8,10) F(9,11) F(12,14) F(13,15) \
  F(16,18) F(17,19) F(20,22) F(21,23) F(24,26) F(25,27) F(28,30) F(29,31) \
  F(32,34) F(33,35) F(36,38) F(37,39) F(40,42) F(41,43) F(44,46) F(45,47) \
  F(48,50) F(49,51) F(52,54) F(53,55) F(56,58) F(57,59) F(60,62) F(61,63)
#define PAIRS1(F) F(0,1) F(2,3) F(4,5) F(6,7) F(8,9) F(10,11) F(12,13) F(14,15) \
  F(16,17) F(18,19) F(20,21) F(22,23) F(24,25) F(26,27) F(28,29) F(30,31) \
  F(32,33) F(34,35) F(36,37) F(38,39) F(40,41) F(42,43) F(44,45) F(46,47) \
  F(48,49) F(50,51) F(52,53) F(54,55) F(56,57) F(58,59) F(60,61) F(62,63)

// ---------------------------------------------------------------------------
template <bool PRE>
__global__ __launch_bounds__(256)
__attribute__((amdgpu_waves_per_eu(4, 4)))
void qsim(const float* __restrict__ feats,
          const float* __restrict__ qp,
          const float* __restrict__ cs,
          float* __restrict__ out)
{
    const int lane = threadIdx.x & 63;
    const int row  = blockIdx.x * 4 + (threadIdx.x >> 6);

    // entangler lane-permutation bpermute byte addresses (GF(2)-linear map)
    const int sl0 = lane ^ (lane >> 1) ^ ((lane >> 2) & 5);
    const int addr0 = sl0 << 2;
    const int addr1 = (sl0 ^ 48) << 2;

#define DCL(r) float v##r;
    ALL64(DCL)
#undef DCL

    // ---- load + tanh + amplitude embedding ----
    const float* fr = feats + (size_t)row * 2048;
    float nrm = 0.f;
#define LD(r) { float x_ = tanhf(fr[((r) << 6) + lane]) * 1.5707963267948966f; \
                v##r = x_; nrm += x_ * x_; }
    LO32(LD)
#undef LD
#pragma unroll
    for (int m = 32; m >= 1; m >>= 1) nrm += __shfl_xor(nrm, m, 64);
    nrm += 512.0f;                       // 2048 pad elements of 0.5^2
    const float inv  = rsqrtf(nrm);
    const float padv = 0.5f * inv;
#define SC(r) v##r *= inv;
    LO32(SC)
#undef SC
#define PD(r) v##r = padv;
    HI32(PD)
#undef PD

    // ---- 20 circuit layers ----
    for (int l = 0; l < LAYERS; ++l) {
        // ---- entangling layer: in-place reg-cycle rename fused with lane bpermute
#define BPV(a, x) __int_as_float(__builtin_amdgcn_ds_bpermute( \
                      (((a) & 1) ? addr1 : addr0), __float_as_int(x)))
#define FIX(a) v##a = BPV(a, v##a);
#define CYC2(a,b) { float t_ = v##a; v##a = BPV(a, v##b); v##b = BPV(b, t_); }
#define CYC4(a,b,c,d) { float t_ = v##a; v##a = BPV(a, v##b); \
        v##b = BPV(b, v##c); v##c = BPV(c, v##d); v##d = BPV(d, t_); }
#define CYC8(a,b,c,d,e,f,g,h) { float t_ = v##a; v##a = BPV(a, v##b); \
        v##b = BPV(b, v##c); v##c = BPV(c, v##d); v##d = BPV(d, v##e); \
        v##e = BPV(e, v##f); v##f = BPV(f, v##g); v##g = BPV(g, v##h); \
        v##h = BPV(h, t_); }
        FIX(0) FIX(1)
        CYC2(2, 3)
        CYC4(4, 7, 5, 6)
        CYC4(8, 12, 11, 14)
        CYC4(9, 13, 10, 15)
        CYC8(16, 28, 23, 25, 17, 29, 22, 24)
        CYC8(18, 31, 21, 26, 19, 30, 20, 27)
        CYC8(32, 48, 44, 59, 34, 51, 46, 56)
        CYC8(33, 49, 45, 58, 35, 50, 47, 57)
        CYC8(36, 55, 41, 61, 38, 52, 43, 62)
        CYC8(37, 54, 40, 60, 39, 53, 42, 63)
#undef BPV
#undef FIX
#undef CYC2
#undef CYC4
#undef CYC8

        const float* csl = cs + l * 24;

        // ---- RY on reg-bit qubits j = 0..5 (mask 32 >> j) — pure VALU
#define RYP(a,b) { float a0_ = v##a, a1_ = v##b; \
        v##a = c_ * a0_ - s_ * a1_; v##b = s_ * a0_ + c_ * a1_; }
#define RYREG(J, LIST) { float c_, s_; \
        if constexpr (PRE) { c_ = csl[2*(J)]; s_ = csl[2*(J)+1]; } \
        else { float t_ = 0.5f * qp[12 + l*12 + (J)]; __sincosf(t_, &s_, &c_); } \
        LIST(RYP) }
        RYREG(0, PAIRS32)
        RYREG(1, PAIRS16)
        RYREG(2, PAIRS8)
        RYREG(3, PAIRS4)
        RYREG(4, PAIRS2)
        RYREG(5, PAIRS1)
#undef RYREG
#undef RYP

        // ---- RY on lane-bit qubits j = 6..11 (lane mask 32 >> (j-6))
#define LRY(r) { float p_ = __shfl_xor(v##r, m, 64); v##r = c_ * v##r + ssel_ * p_; }
#pragma unroll
        for (int j = 0; j < 6; ++j) {
            float c_, s_;
            if constexpr (PRE) { c_ = csl[12 + 2*j]; s_ = csl[12 + 2*j + 1]; }
            else { float t_ = 0.5f * qp[12 + l*12 + 6 + j]; __sincosf(t_, &s_, &c_); }
            const int m = 32 >> j;
            const float ssel_ = (lane & m) ? s_ : -s_;
            ALL64(LRY)
        }
#undef LRY
    }

    // ---- PauliZ expectation values ----
    float T = 0.f;
#define SQT(r) v##r *= v##r; T += v##r;
    ALL64(SQT)
#undef SQT

    float part[12];
#define ADDB(a,b) + v##b
    { float S;
      S = 0.f PAIRS32(ADDB); part[0] = T - 2.f * S;
      S = 0.f PAIRS16(ADDB); part[1] = T - 2.f * S;
      S = 0.f PAIRS8(ADDB);  part[2] = T - 2.f * S;
      S = 0.f PAIRS4(ADDB);  part[3] = T - 2.f * S;
      S = 0.f PAIRS2(ADDB);  part[4] = T - 2.f * S;
      S = 0.f PAIRS1(ADDB);  part[5] = T - 2.f * S; }
#undef ADDB
#pragma unroll
    for (int q = 6; q < 12; ++q) {
        const int m = 32 >> (q - 6);
        part[q] = (lane & m) ? -T : T;
    }
#pragma unroll
    for (int q = 0; q < 12; ++q) {
#pragma unroll
        for (int m2 = 32; m2 >= 1; m2 >>= 1) part[q] += __shfl_xor(part[q], m2, 64);
    }
    if (lane == 0) {
#pragma unroll
        for (int q = 0; q < 12; ++q) out[row * 12 + q] = part[q];
    }
}

// ---------------------------------------------------------------------------
extern "C" void kernel_launch(void* const* d_in, const int* in_sizes, int n_in,
                              void* d_out, int out_size, void* d_ws, size_t ws_size,
                              hipStream_t stream) {
    (void)in_sizes; (void)n_in; (void)out_size;
    const float* feats = (const float*)d_in[0];   // (4096, 2048) fp32
    const float* qp    = (const float*)d_in[1];   // (252,) fp32
    float* out = (float*)d_out;                   // (4096, 12) fp32

    if (ws_size >= CS_FLOATS * sizeof(float)) {
        float* cs = (float*)d_ws;
        cs_precompute<<<1, 256, 0, stream>>>(qp, cs);
        qsim<true><<<1024, 256, 0, stream>>>(feats, qp, cs, out);
    } else {
        qsim<false><<<1024, 256, 0, stream>>>(feats, qp, nullptr, out);
    }
}